// Round 8
// baseline (40.633 us; speedup 1.0000x reference)
//
#include <hip/hip_runtime.h>

// Problem: x [B=64, C=512, H=28, W=28] fp32.
// Forward math reduces to: out = relu(x - mean_over_C(x)) per (b,h,w).
// (top_k mask and stop_gradient only affect the backward pass.)
//
// Round-6 (3rd submit; container unresponsive, not a kernel failure):
// join-depth experiment. EA throughput pinned at ~4.1 TB/s across three
// structures (TX/occupancy/nt all <2% movement). Last untested lever:
// per-wave burstiness. CPT 16->32 (block 256, TY=16) halves the number of
// hard joins + barriers per byte and doubles outstanding loads per wave.
//  - still single global read, register-resident (32 float4 live), 1 barrier
//  - 256B contiguous segments, nt stores (best known config otherwise)
//  - __launch_bounds__(256,3): cap VGPR at 170 so 3 waves/SIMD = 12/CU,
//    matching the 784-block (3.06/CU) demand exactly.

#define B_DIM 64
#define C_DIM 512
#define HW4   196               // 28*28/4 float4 groups per (b,c)
#define TX    16                // float4-groups per block (256B segments)
#define TY    16                // channel slices
#define CPT   (C_DIM / TY)      // 32 channels per thread
#define NW    4                 // waves per block (256 threads)

typedef __attribute__((ext_vector_type(4))) float f4;

__global__ __launch_bounds__(256, 3) void kwinners_fwd(const float* __restrict__ x,
                                                       float* __restrict__ out) {
    __shared__ f4 part[NW][TX];     // 1 KB

    const int tid = threadIdx.x;
    const int tx  = tid & (TX - 1);     // 0..15
    const int ty  = tid >> 4;           // 0..15
    const int w   = tid >> 6;           // wave id 0..3

    const int g   = blockIdx.x * TX + tx;   // global float4-group index
    const int b   = g / HW4;
    const int hw4 = g - b * HW4;

    const f4* __restrict__ xb =
        reinterpret_cast<const f4*>(x) + (size_t)b * C_DIM * HW4 + hw4;
    f4* __restrict__ ob =
        reinterpret_cast<f4*>(out) + (size_t)b * C_DIM * HW4 + hw4;

    const int c0 = ty * CPT;

    // ---- single global read: 32 float4 into registers (deep burst) ----
    f4 v[CPT];
    #pragma unroll
    for (int cc = 0; cc < CPT; ++cc) {
        v[cc] = xb[(c0 + cc) * HW4];
    }

    // ---- per-thread partial sum ----
    f4 s = (f4)(0.0f);
    #pragma unroll
    for (int cc = 0; cc < CPT; ++cc) s += v[cc];

    // ---- wave-level reduce: lanes sharing tx differ in tid bits 4,5 ----
    #pragma unroll
    for (int m = 16; m <= 32; m <<= 1) {
        s.x += __shfl_xor(s.x, m);
        s.y += __shfl_xor(s.y, m);
        s.z += __shfl_xor(s.z, m);
        s.w += __shfl_xor(s.w, m);
    }

    // ---- combine the 4 per-wave partials (one barrier) ----
    if ((tid & 63) < TX) part[w][tx] = s;
    __syncthreads();

    f4 m4 = (f4)(0.0f);
    #pragma unroll
    for (int ww = 0; ww < NW; ++ww) m4 += part[ww][tx];
    m4 *= (1.0f / (float)C_DIM);

    // ---- store relu(v - mean) from registers, non-temporal ----
    #pragma unroll
    for (int cc = 0; cc < CPT; ++cc) {
        f4 r = v[cc] - m4;
        r.x = fmaxf(r.x, 0.f);
        r.y = fmaxf(r.y, 0.f);
        r.z = fmaxf(r.z, 0.f);
        r.w = fmaxf(r.w, 0.f);
        __builtin_nontemporal_store(r, &ob[(cc + c0) * HW4]);
    }
}

extern "C" void kernel_launch(void* const* d_in, const int* in_sizes, int n_in,
                              void* d_out, int out_size, void* d_ws, size_t ws_size,
                              hipStream_t stream) {
    const float* x  = (const float*)d_in[0];   // [B, C, H, W] fp32
    float* out = (float*)d_out;

    const int groups = B_DIM * HW4;            // 12544 float4 groups
    dim3 grid(groups / TX);                    // 784 blocks x 4 waves
    dim3 block(256);
    hipLaunchKernelGGL(kwinners_fwd, grid, block, 0, stream, x, out);
}

// Round 11
// 40.612 us; speedup vs baseline: 1.0005x; 1.0005x over previous
//
#include <hip/hip_runtime.h>

// Problem: x [B=64, C=512, H=28, W=28] fp32.
// Forward math reduces to: out = relu(x - mean_over_C(x)) per (b,h,w).
//
// Round-11: force TRUE register residency. VGPR counts (28/44/76 across
// rounds vs 32/64/128 needed) prove the compiler has been rematerializing
// the loads for the store phase -> every kernel so far was two-pass via
// L2/MALL. Launder each loaded value through empty asm ("+v") so it cannot
// be rematerialized; the load then happens exactly once.
//  - round-5 structure otherwise (TX=16, TY=32, CPT=16, 512 thr, 1 barrier)
//  - __builtin_nontemporal_store (the sc0 sc1 asm bypass broke readback
//    coherency in round 10: harness saw stale memset zeros in L2)
//  - no min-waves cap: give the allocator room for 64 data VGPRs

#define B_DIM 64
#define C_DIM 512
#define HW4   196               // 28*28/4 float4 groups per (b,c)
#define TX    16                // float4-groups per block (256B segments)
#define TY    32                // channel slices
#define CPT   (C_DIM / TY)      // 16 channels per thread
#define NW    8                 // waves per block (512 threads)

typedef __attribute__((ext_vector_type(4))) float f4;

__global__ __launch_bounds__(512) void kwinners_fwd(const float* __restrict__ x,
                                                    float* __restrict__ out) {
    __shared__ f4 part[NW][TX];     // 2 KB

    const int tid = threadIdx.x;
    const int tx  = tid & (TX - 1);     // 0..15
    const int ty  = tid >> 4;           // 0..31
    const int w   = tid >> 6;           // wave id 0..7

    const int g   = blockIdx.x * TX + tx;   // global float4-group index
    const int b   = g / HW4;
    const int hw4 = g - b * HW4;

    const f4* __restrict__ xb =
        reinterpret_cast<const f4*>(x) + (size_t)b * C_DIM * HW4 + hw4;
    f4* __restrict__ ob =
        reinterpret_cast<f4*>(out) + (size_t)b * C_DIM * HW4 + hw4;

    const int c0 = ty * CPT;

    // ---- single global read: 16 float4 into registers, PINNED ----
    f4 v[CPT];
    #pragma unroll
    for (int cc = 0; cc < CPT; ++cc) {
        v[cc] = xb[(c0 + cc) * HW4];
        // opaque value transform: compiler cannot re-load/rematerialize v[cc]
        asm volatile("" : "+v"(v[cc]));
    }

    // ---- per-thread partial sum ----
    f4 s = (f4)(0.0f);
    #pragma unroll
    for (int cc = 0; cc < CPT; ++cc) s += v[cc];

    // ---- wave-level reduce: lanes sharing tx differ in tid bits 4,5 ----
    #pragma unroll
    for (int m = 16; m <= 32; m <<= 1) {
        s.x += __shfl_xor(s.x, m);
        s.y += __shfl_xor(s.y, m);
        s.z += __shfl_xor(s.z, m);
        s.w += __shfl_xor(s.w, m);
    }

    // ---- combine the 8 per-wave partials (one barrier) ----
    if ((tid & 63) < TX) part[w][tx] = s;
    __syncthreads();

    f4 m4 = (f4)(0.0f);
    #pragma unroll
    for (int ww = 0; ww < NW; ++ww) m4 += part[ww][tx];
    m4 *= (1.0f / (float)C_DIM);

    // ---- store relu(v - mean) from the pinned registers, non-temporal ----
    #pragma unroll
    for (int cc = 0; cc < CPT; ++cc) {
        f4 r = v[cc] - m4;
        r.x = fmaxf(r.x, 0.f);
        r.y = fmaxf(r.y, 0.f);
        r.z = fmaxf(r.z, 0.f);
        r.w = fmaxf(r.w, 0.f);
        __builtin_nontemporal_store(r, &ob[(c0 + cc) * HW4]);
    }
}

extern "C" void kernel_launch(void* const* d_in, const int* in_sizes, int n_in,
                              void* d_out, int out_size, void* d_ws, size_t ws_size,
                              hipStream_t stream) {
    const float* x  = (const float*)d_in[0];   // [B, C, H, W] fp32
    float* out = (float*)d_out;

    const int groups = B_DIM * HW4;            // 12544 float4 groups
    dim3 grid(groups / TX);                    // 784 blocks x 8 waves
    dim3 block(512);
    hipLaunchKernelGGL(kwinners_fwd, grid, block, 0, stream, x, out);
}